// Round 8
// baseline (342.775 us; speedup 1.0000x reference)
//
#include <hip/hip_runtime.h>

#define NB 4
#define NC 256
#define NH 128
#define NW 256
#define ND 48
#define NHW (NH * NW)
#define CC 16            /* channels per chunk */
#define NCHUNK (NC / CC) /* 16 */
#define RW (NW + ND)     /* 304 */

__device__ inline void async16(void* lds, const void* g) {
  __builtin_amdgcn_global_load_lds(
      (const __attribute__((address_space(1))) void*)g,
      (__attribute__((address_space(3))) void*)lds,
      16, 0, 0);
}

__global__ __launch_bounds__(256, 2)
void corr_vol_kernel(const float* __restrict__ Lf,
                     const float* __restrict__ Rf,
                     float* __restrict__ out) {
  __shared__ float Lt[2][CC][NW];   // 2 x 16 KB
  __shared__ float Rt[2][CC][RW];   // 2 x 19 KB
  __shared__ float nL[NW];
  __shared__ float nR[RW];

  const int tid  = threadIdx.x;
  const int lane = tid & 63;
  const int wv   = tid >> 6;          // wave id 0..3
  const int b    = blockIdx.x >> 7;
  const int h    = blockIdx.x & 127;

  const float* Lb = Lf + ((size_t)b * NC) * NHW + (size_t)h * NW;
  const float* Rb = Rf + ((size_t)b * NC) * NHW + (size_t)h * NW;

  // zero persistent left halo of both R buffers (stages never touch cols < ND)
  for (int idx = tid; idx < 2 * CC * ND; idx += 256) {
    const int bufi = idx / (CC * ND);
    const int rem  = idx % (CC * ND);
    Rt[bufi][rem / ND][rem % ND] = 0.0f;
  }
  if (tid < ND) nR[tid] = 0.0f;
  __syncthreads();

  // thread tiling: 4 consecutive w, 12 consecutive i
  const int w0 = (tid & 63) << 2;     // 0..252
  const int i0 = (tid >> 6) * 12;     // 0,12,24,36 (wave-uniform)
  const int rb = w0 + 36 - i0;        // 16B-aligned R read base

  float acc[4][12];
  #pragma unroll
  for (int a = 0; a < 4; ++a)
    #pragma unroll
    for (int q = 0; q < 12; ++q) acc[a][q] = 0.0f;

  float l2 = 0.0f, r2 = 0.0f;

  // ---- prologue: stage chunk 0 into buffer 0 (8 loads per wave) ----
  #pragma unroll
  for (int j = 0; j < 4; ++j) {
    const int cl = wv * 4 + j;
    const size_t go = (size_t)cl * NHW + (size_t)(lane * 4);
    async16(&Lt[0][cl][0],  Lb + go);
    async16(&Rt[0][cl][ND], Rb + go);
  }

  for (int k = 0; k < NCHUNK; ++k) {
    const int cur = k & 1;
    if (k + 1 < NCHUNK) {
      // issue next chunk's loads (8 per wave), then wait only for current's
      const int nxt = cur ^ 1;
      const size_t coff = (size_t)((k + 1) * CC) * NHW;
      #pragma unroll
      for (int j = 0; j < 4; ++j) {
        const int cl = wv * 4 + j;
        const size_t go = coff + (size_t)cl * NHW + (size_t)(lane * 4);
        async16(&Lt[nxt][cl][0],  Lb + go);
        async16(&Rt[nxt][cl][ND], Rb + go);
      }
      asm volatile("s_waitcnt vmcnt(8)" ::: "memory");  // current chunk landed; next 8 in flight
    } else {
      asm volatile("s_waitcnt vmcnt(0)" ::: "memory");  // last chunk: drain
    }
    __builtin_amdgcn_s_barrier();   // all waves' current-chunk loads visible

    // ---- norm accumulation: thread t owns column t ----
    #pragma unroll 8
    for (int c = 0; c < CC; ++c) {
      const float lv = Lt[cur][c][tid];
      const float rv = Rt[cur][c][tid + ND];
      l2 = fmaf(lv, lv, l2);
      r2 = fmaf(rv, rv, r2);
    }

    // ---- main correlation: per channel 5x ds_read_b128 + 48 FMA ----
    #pragma unroll 4
    for (int c = 0; c < CC; ++c) {
      const float4 lv4 = *reinterpret_cast<const float4*>(&Lt[cur][c][w0]);
      const float4 r0v = *reinterpret_cast<const float4*>(&Rt[cur][c][rb]);
      const float4 r1v = *reinterpret_cast<const float4*>(&Rt[cur][c][rb + 4]);
      const float4 r2v = *reinterpret_cast<const float4*>(&Rt[cur][c][rb + 8]);
      const float4 r3v = *reinterpret_cast<const float4*>(&Rt[cur][c][rb + 12]);
      const float ll[4] = {lv4.x, lv4.y, lv4.z, lv4.w};
      const float rr[16] = {r0v.x, r0v.y, r0v.z, r0v.w,
                            r1v.x, r1v.y, r1v.z, r1v.w,
                            r2v.x, r2v.y, r2v.z, r2v.w,
                            r3v.x, r3v.y, r3v.z, r3v.w};
      #pragma unroll
      for (int dw = 0; dw < 4; ++dw) {
        #pragma unroll
        for (int di = 0; di < 12; ++di) {
          // rr index = (w - i + 48) - rb = dw - di + 12  (in [1,15])
          acc[dw][di] = fmaf(ll[dw], rr[dw - di + 12], acc[dw][di]);
        }
      }
    }
    __builtin_amdgcn_s_barrier();   // readers done before next stage overwrites
  }

  // ---- publish norms ----
  nL[tid] = l2;
  nR[tid + ND] = r2;
  __syncthreads();

  float invL[4];
  #pragma unroll
  for (int a = 0; a < 4; ++a)
    invL[a] = 1.0f / fmaxf(sqrtf(nL[w0 + a]), 1e-12f);

  const int jb = w0 - i0 + ND;
  float invR[15];
  #pragma unroll
  for (int k = 0; k < 15; ++k)
    invR[k] = 1.0f / fmaxf(sqrtf(nR[jb - 11 + k]), 1e-12f);

  // ---- scale + write: 12 coalesced float4 stores per thread ----
  #pragma unroll
  for (int di = 0; di < 12; ++di) {
    const int i = i0 + di;
    float4 v;
    v.x = acc[0][di] * invL[0] * invR[0 - di + 11];
    v.y = acc[1][di] * invL[1] * invR[1 - di + 11];
    v.z = acc[2][di] * invL[2] * invR[2 - di + 11];
    v.w = acc[3][di] * invL[3] * invR[3 - di + 11];
    *reinterpret_cast<float4*>(out + ((size_t)(b * ND + i) * NH + h) * NW + w0) = v;
  }
}

extern "C" void kernel_launch(void* const* d_in, const int* in_sizes, int n_in,
                              void* d_out, int out_size, void* d_ws, size_t ws_size,
                              hipStream_t stream) {
  const float* Lf = (const float*)d_in[0];
  const float* Rf = (const float*)d_in[1];
  float* out = (float*)d_out;
  dim3 grid(NB * NH);
  dim3 block(256);
  corr_vol_kernel<<<grid, block, 0, stream>>>(Lf, Rf, out);
}

// Round 10
// 317.842 us; speedup vs baseline: 1.0784x; 1.0784x over previous
//
#include <hip/hip_runtime.h>

#define NB 4
#define NC 256
#define NH 128
#define NW 256
#define ND 48
#define NHW (NH * NW)

__global__ __launch_bounds__(256, 2)
void corr_vol_kernel(const float* __restrict__ Lf,
                     const float* __restrict__ Rf,
                     float* __restrict__ out) {
  const int tid = threadIdx.x;
  const int b   = blockIdx.x >> 7;   // /128
  const int h   = blockIdx.x & 127;
  const int w0  = (tid & 63) << 2;   // 0..252
  const int i0  = (tid >> 6) * 12;   // 0,12,24,36

  // flat float offsets (max ~33.5M < 2^31, fits int)
  const int rowbase = (b * NC * NH + h) * NW;
  int lOff = rowbase + w0;
  int rOff = rowbase + w0 - i0 - 12;   // R window start: w' = w0-i0-12

  float acc[4][12];
  float l2[4] = {0.f, 0.f, 0.f, 0.f};
  float r2[16];
  #pragma unroll
  for (int q = 0; q < 16; ++q) r2[q] = 0.f;
  #pragma unroll
  for (int a = 0; a < 4; ++a)
    #pragma unroll
    for (int d = 0; d < 12; ++d) acc[a][d] = 0.f;

  // Streaming main loop: no LDS, no barriers. All loads coalesced
  // (lane-consecutive float4). Negative-w' quads are address-clamped to 0:
  // values are garbage but only feed outputs with w < i, which are
  // zero-written in the epilogue. Quads are fully-valid or fully-garbage
  // since rOff ≡ 0 (mod 4).
  #pragma unroll 2
  for (int c = 0; c < NC; ++c) {
    const float4 lv  = *reinterpret_cast<const float4*>(Lf + lOff);
    const float4 rq0 = *reinterpret_cast<const float4*>(Rf + (rOff      > 0 ? rOff      : 0));
    const float4 rq1 = *reinterpret_cast<const float4*>(Rf + (rOff + 4  > 0 ? rOff + 4  : 0));
    const float4 rq2 = *reinterpret_cast<const float4*>(Rf + (rOff + 8  > 0 ? rOff + 8  : 0));
    const float4 rq3 = *reinterpret_cast<const float4*>(Rf + (rOff + 12 > 0 ? rOff + 12 : 0));
    lOff += NHW;
    rOff += NHW;

    const float ll[4]  = {lv.x, lv.y, lv.z, lv.w};
    const float rr[16] = {rq0.x, rq0.y, rq0.z, rq0.w,
                          rq1.x, rq1.y, rq1.z, rq1.w,
                          rq2.x, rq2.y, rq2.z, rq2.w,
                          rq3.x, rq3.y, rq3.z, rq3.w};

    // norms for this thread's own output columns
    #pragma unroll
    for (int a = 0; a < 4; ++a) l2[a] = fmaf(ll[a], ll[a], l2[a]);
    #pragma unroll
    for (int q = 1; q < 16; ++q) r2[q] = fmaf(rr[q], rr[q], r2[q]);  // idx 0 unused

    // correlation: rr index = dw - di + 12 ∈ [1,15]
    #pragma unroll
    for (int dw = 0; dw < 4; ++dw)
      #pragma unroll
      for (int di = 0; di < 12; ++di)
        acc[dw][di] = fmaf(ll[dw], rr[dw - di + 12], acc[dw][di]);
  }

  // per-thread normalization factors (F.normalize semantics: x/max(||x||,eps))
  float invL[4];
  #pragma unroll
  for (int a = 0; a < 4; ++a)
    invL[a] = 1.0f / fmaxf(sqrtf(l2[a]), 1e-12f);
  float invR[16];
  invR[0] = 0.0f;
  #pragma unroll
  for (int q = 1; q < 16; ++q)
    invR[q] = 1.0f / fmaxf(sqrtf(r2[q]), 1e-12f);

  // scale + zero-mask (w < i → exact 0) + coalesced float4 stores
  #pragma unroll
  for (int di = 0; di < 12; ++di) {
    const int i = i0 + di;
    float4 v;
    v.x = (w0 + 0 >= i) ? acc[0][di] * invL[0] * invR[0 - di + 12] : 0.0f;
    v.y = (w0 + 1 >= i) ? acc[1][di] * invL[1] * invR[1 - di + 12] : 0.0f;
    v.z = (w0 + 2 >= i) ? acc[2][di] * invL[2] * invR[2 - di + 12] : 0.0f;
    v.w = (w0 + 3 >= i) ? acc[3][di] * invL[3] * invR[3 - di + 12] : 0.0f;
    *reinterpret_cast<float4*>(out + ((size_t)(b * ND + i) * NH + h) * NW + w0) = v;
  }
}

extern "C" void kernel_launch(void* const* d_in, const int* in_sizes, int n_in,
                              void* d_out, int out_size, void* d_ws, size_t ws_size,
                              hipStream_t stream) {
  const float* Lf = (const float*)d_in[0];
  const float* Rf = (const float*)d_in[1];
  float* out = (float*)d_out;
  dim3 grid(NB * NH);
  dim3 block(256);
  corr_vol_kernel<<<grid, block, 0, stream>>>(Lf, Rf, out);
}